// Round 8
// baseline (1889.588 us; speedup 1.0000x reference)
//
#include <hip/hip_runtime.h>
#include <hip/hip_fp16.h>
#include <cstdint>
#include <cstddef>

#define H 128
#define C 64
#define KITER 10
#define SCHUNK 4096

// ---------------- setup kernels ----------------

__global__ void k_zero(int* __restrict__ deg, double* __restrict__ stats, int n, int nstats) {
    int i = blockIdx.x * blockDim.x + threadIdx.x;
    if (i < n) deg[i] = 0;
    if (i < nstats) stats[i] = 0.0;
}

__global__ void k_degcount(const int* __restrict__ dst, int* __restrict__ deg, int E) {
    int e = blockIdx.x * blockDim.x + threadIdx.x;
    if (e < E) atomicAdd(&deg[dst[e]], 1);
}

// ---- multi-block exclusive scan of deg -> row_ptr/row_cur ----

__global__ __launch_bounds__(256) void k_blocksum(const int* __restrict__ deg,
                                                  int* __restrict__ bsum, int n) {
    __shared__ int red[256];
    int t = threadIdx.x;
    int i = blockIdx.x * 256 + t;
    red[t] = (i < n) ? deg[i] : 0;
    __syncthreads();
    for (int off = 128; off >= 1; off >>= 1) {
        if (t < off) red[t] += red[t + off];
        __syncthreads();
    }
    if (t == 0) bsum[blockIdx.x] = red[0];
}

__global__ __launch_bounds__(512) void k_scanb(const int* __restrict__ bsum,
                                               int* __restrict__ boff,
                                               int* __restrict__ row_ptr, int nb, int n) {
    __shared__ int s[512];
    int t = threadIdx.x;
    int v = (t < nb) ? bsum[t] : 0;
    s[t] = v;
    __syncthreads();
    for (int off = 1; off < 512; off <<= 1) {
        int u = (t >= off) ? s[t - off] : 0;
        __syncthreads();
        s[t] += u;
        __syncthreads();
    }
    if (t < nb) boff[t] = s[t] - v;  // exclusive
    if (t == 511) row_ptr[n] = s[511];
}

__global__ __launch_bounds__(256) void k_fill(const int* __restrict__ deg,
                                              const int* __restrict__ boff,
                                              int* __restrict__ row_ptr,
                                              int* __restrict__ row_cur, int n) {
    __shared__ int s[256];
    int t = threadIdx.x;
    int i = blockIdx.x * 256 + t;
    int d = (i < n) ? deg[i] : 0;
    s[t] = d;
    __syncthreads();
    for (int off = 1; off < 256; off <<= 1) {
        int u = (t >= off) ? s[t - off] : 0;
        __syncthreads();
        s[t] += u;
        __syncthreads();
    }
    if (i < n) {
        int base = boff[blockIdx.x] + s[t] - d;
        row_ptr[i] = base;
        row_cur[i] = base;
    }
}

__global__ void k_norm(const int* __restrict__ deg, float* __restrict__ degc,
                       float* __restrict__ nrm, int n) {
    int i = blockIdx.x * blockDim.x + threadIdx.x;
    if (i < n) {
        int d = deg[i];
        float dc = (float)(d > 1 ? d : 1);
        degc[i] = dc;
        nrm[i] = (float)(1.0 / sqrt((double)dc));  // correctly-rounded dc^-0.5
    }
}

// XCD-sliced scatter (R4: confirmed WRITE_SIZE collapse).
__global__ __launch_bounds__(256) void k_scatter8(const int* __restrict__ src,
                                                  const int* __restrict__ dst,
                                                  int* __restrict__ row_cur,
                                                  int* __restrict__ csr_src,
                                                  int E, int slice_sz) {
    int chunk = blockIdx.x >> 3;
    int xcd = blockIdx.x & 7;
    int base = chunk * SCHUNK;
    int lo_node = xcd * slice_sz;
    int hi_node = lo_node + slice_sz;
    #pragma unroll
    for (int r = 0; r < SCHUNK; r += 256) {
        int e = base + r + threadIdx.x;
        if (e < E) {
            int d = dst[e];
            if (d >= lo_node && d < hi_node) {
                int pos = atomicAdd(&row_cur[d], 1);
                csr_src[pos] = src[e];
            }
        }
    }
}

__device__ inline uint32_t pack_h2(float x, float y) {
    __half2 h = __floats2half2_rn(x, y);
    return __builtin_bit_cast(uint32_t, h);
}
__device__ inline float2 unpack_h2(uint32_t p) {
    __half2 h = __builtin_bit_cast(__half2, p);
    return __half22float2(h);
}

// featn0 = feat * norm (f32 master) + fp16 mirror. thread per float4.
__global__ __launch_bounds__(256) void k_scale(const float* __restrict__ feat,
                                               const float* __restrict__ nrm,
                                               float* __restrict__ featn,
                                               uint32_t* __restrict__ mir, int n4) {
    int i = blockIdx.x * blockDim.x + threadIdx.x;
    if (i >= n4) return;
    int node = i >> 5;  // 32 float4 per row (H=128)
    float nn = nrm[node];
    float4 v = ((const float4*)feat)[i];
    v.x *= nn; v.y *= nn; v.z *= nn; v.w *= nn;
    ((float4*)featn)[i] = v;
    mir[i * 2]     = pack_h2(v.x, v.y);
    mir[i * 2 + 1] = pack_h2(v.z, v.w);
}

// ---------------- per-iteration kernels ----------------

__global__ __launch_bounds__(256) void k_pred0(const float* __restrict__ logits,
                                               int* __restrict__ pred, int n) {
    int wid = (blockIdx.x * blockDim.x + threadIdx.x) >> 6;
    int lane = threadIdx.x & 63;
    if (wid >= n) return;
    float v = logits[(size_t)wid * C + lane];
    int idx = lane;
    #pragma unroll
    for (int off = 1; off < 64; off <<= 1) {
        float ov = __shfl_xor(v, off);
        int oi = __shfl_xor(idx, off);
        if (ov > v || (ov == v && oi < idx)) { v = ov; idx = oi; }
    }
    if (lane == 0) pred[wid] = idx;
}

// thread-per-node logits = featn@w + b, pred = argmax (featn f32 master).
// TB=64: grid 1563 blocks -> fine-grained CU load balance (391x256 gave a
// 2x sequential-block tail on half the CUs).
__global__ __launch_bounds__(64) void k_predG(const float* __restrict__ featn,
                                              const float* __restrict__ w_y,
                                              const float* __restrict__ b_y,
                                              int* __restrict__ pred, int n) {
    int node = blockIdx.x * blockDim.x + threadIdx.x;
    bool act = node < n;
    int ld = act ? node : 0;
    const float4* p4 = (const float4*)(featn + (size_t)ld * H);
    float fv[H];
    #pragma unroll
    for (int q = 0; q < H / 4; ++q) {
        float4 t = p4[q];
        fv[q * 4 + 0] = t.x;
        fv[q * 4 + 1] = t.y;
        fv[q * 4 + 2] = t.z;
        fv[q * 4 + 3] = t.w;
    }
    float best = -3.402823466e+38f;
    int bi = 0;
    for (int cb = 0; cb < C / 8; ++cb) {
        float acc[8];
        #pragma unroll
        for (int u = 0; u < 8; ++u) acc[u] = 0.f;
        const float* wp = w_y + cb * 8;
        #pragma unroll
        for (int h = 0; h < H; ++h) {
            #pragma unroll
            for (int u = 0; u < 8; ++u)
                acc[u] = fmaf(fv[h], wp[h * C + u], acc[u]);
        }
        #pragma unroll
        for (int u = 0; u < 8; ++u) {
            float val = acc[u] + b_y[cb * 8 + u];
            int c = cb * 8 + u;
            if (val > best) { best = val; bi = c; }  // strict > keeps first index
        }
    }
    if (act) pred[node] = bi;
}

// Thread-per-node edge features, TB=64 (granularity), present-classes-only
// entropy via seen-mask, single-wave f64 butterfly for the 4 stat sums.
__global__ __launch_bounds__(64) void k_edge(const int* __restrict__ row_ptr,
                                             const int* __restrict__ csr_src,
                                             const int* __restrict__ pred,
                                             const float* __restrict__ degc,
                                             float* __restrict__ f1, float* __restrict__ f2,
                                             double* __restrict__ stats_iter, int n) {
    __shared__ unsigned char hist[64][64];
    int t = threadIdx.x;
    int node = blockIdx.x * 64 + t;
    uint32_t* hp = (uint32_t*)hist[t];
    #pragma unroll
    for (int q = 0; q < 16; ++q) hp[q] = 0u;
    float v1 = 0.f, v2 = 0.f;
    bool act = node < n;
    if (act) {
        int lo = row_ptr[node], hi = row_ptr[node + 1];
        int pc = pred[node];
        int eq = 0;
        uint64_t seen = 0;
        for (int j = lo; j < hi; ++j) {
            int p = pred[csr_src[j]];
            eq += (p == pc) ? 1 : 0;
            hist[t][p] += 1;
            seen |= 1ull << p;
        }
        float dc = degc[node];
        v1 = (float)eq / dc;
        int nnz = __popcll(seen);
        float s = 0.f;
        uint64_t m = seen;
        while (m) {
            int c = __builtin_ctzll(m);
            m &= m - 1;
            float cv = (float)hist[t][c] / dc;  // >= 1/dc >> 1e-5, clamp dead
            s += cv * logf(cv);
        }
        const float c0 = 1e-5f * -11.5129251f;  // 1e-5*ln(1e-5) in f32
        s += (float)(64 - nnz) * c0;
        v2 = -s;
        f1[node] = v1;
        f2[node] = v2;
    }
    // single-wave butterfly for the 4 f64 stat sums, then 4 atomics.
    double vals[4];
    vals[0] = act ? (double)v1 : 0.0;
    vals[1] = vals[0] * vals[0];
    vals[2] = act ? (double)v2 : 0.0;
    vals[3] = vals[2] * vals[2];
    #pragma unroll
    for (int q = 0; q < 4; ++q) {
        #pragma unroll
        for (int off = 1; off < 64; off <<= 1)
            vals[q] += __shfl_xor(vals[q], off);
    }
    if (t < 4) atomicAdd(&stats_iter[t], vals[t]);
}

// SpMM gathering from fp16 mirror, f32 accumulate, + z + residual on f32 master.
// LN-stat finalize in f32 (was f64: ~500 serial cycles/wave of unpipelined
// f64 div/sqrt across 100k waves; f32 rel err ~2e-6 on z, invisible).
__global__ __launch_bounds__(256) void k_spmm(const float* __restrict__ featn,
                                              const uint32_t* __restrict__ mir_cur,
                                              float* __restrict__ nxt,
                                              uint32_t* __restrict__ mir_nxt,
                                              const float* __restrict__ nrm,
                                              const int* __restrict__ row_ptr,
                                              const int* __restrict__ csr_src,
                                              const float* __restrict__ f1,
                                              const float* __restrict__ f2,
                                              const double* __restrict__ stats_iter,
                                              const float* __restrict__ tau1,
                                              const float* __restrict__ tau2,
                                              int n, float fN, int last) {
    int wid = (blockIdx.x * blockDim.x + threadIdx.x) >> 6;
    int lane = threadIdx.x & 63;
    if (wid >= n) return;
    int node = __builtin_amdgcn_readfirstlane(wid);

    // z from global-LN(f1), LN(f2) stats (f32 math on f64 sums)
    float S1 = (float)stats_iter[0], Q1 = (float)stats_iter[1];
    float S2 = (float)stats_iter[2], Q2 = (float)stats_iter[3];
    float m1 = S1 / fN, m2 = S2 / fN;
    float rs1 = 1.0f / sqrtf(Q1 / fN - m1 * m1 + 1e-5f);
    float rs2 = 1.0f / sqrtf(Q2 / fN - m2 * m2 + 1e-5f);
    float ln1 = (f1[node] - m1) * rs1;
    float ln2 = (f2[node] - m2) * rs2;
    float z1 = 1.f / (1.f + expf(ln1 - tau1[0]));  // sigmoid(-(ln1 - tau1))
    float z2 = 1.f / (1.f + expf(ln2 - tau2[0]));
    float z = z1 * z2;

    float nr = nrm[node];
    int lo = row_ptr[node], hi = row_ptr[node + 1];
    float ax = 0.f, ay = 0.f;
    const uint32_t* basep = mir_cur + lane;  // row stride = 64 dwords (128 halves)
    int j = lo;
    for (; j + 3 < hi; j += 4) {
        int s0 = csr_src[j];
        int s1 = csr_src[j + 1];
        int s2 = csr_src[j + 2];
        int s3 = csr_src[j + 3];
        uint32_t p0 = basep[(size_t)s0 * 64];
        uint32_t p1 = basep[(size_t)s1 * 64];
        uint32_t p2 = basep[(size_t)s2 * 64];
        uint32_t p3 = basep[(size_t)s3 * 64];
        float2 f0 = unpack_h2(p0); ax += f0.x; ay += f0.y;
        float2 g1 = unpack_h2(p1); ax += g1.x; ay += g1.y;
        float2 g2 = unpack_h2(p2); ax += g2.x; ay += g2.y;
        float2 g3 = unpack_h2(p3); ax += g3.x; ay += g3.y;
    }
    for (; j < hi; ++j) {
        int s0 = csr_src[j];
        float2 f0 = unpack_h2(basep[(size_t)s0 * 64]);
        ax += f0.x; ay += f0.y;
    }
    const float2 ownn = *(const float2*)(featn + (size_t)node * H + lane * 2);
    float ox = fmaf(z, ax * nr, ownn.x);
    float oy = fmaf(z, ay * nr, ownn.y);
    if (!last) {
        ox *= nr; oy *= nr;  // pre-apply next iter's leading feat*norm
        mir_nxt[(size_t)node * 64 + lane] = pack_h2(ox, oy);
    }
    float2 o; o.x = ox; o.y = oy;
    *(float2*)(nxt + (size_t)node * H + lane * 2) = o;
}

// ---------------- host ----------------

extern "C" void kernel_launch(void* const* d_in, const int* in_sizes, int n_in,
                              void* d_out, int out_size, void* d_ws, size_t ws_size,
                              hipStream_t stream) {
    const float* feat   = (const float*)d_in[0];
    const float* logits = (const float*)d_in[1];
    const float* w_y    = (const float*)d_in[2];
    const float* b_y    = (const float*)d_in[3];
    const float* tau1   = (const float*)d_in[4];
    const float* tau2   = (const float*)d_in[5];
    const int*   src    = (const int*)d_in[6];
    const int*   dst    = (const int*)d_in[7];

    const int N = in_sizes[0] / H;
    const int E = in_sizes[6];
    float* out = (float*)d_out;

    char* ws = (char*)d_ws;
    size_t off = 0;
    auto carve = [&](size_t bytes) -> char* {
        char* p = ws + off;
        off = (off + bytes + 255) & ~(size_t)255;
        return p;
    };
    float*    featnA  = (float*)carve((size_t)N * H * sizeof(float));
    float*    featnB  = (float*)carve((size_t)N * H * sizeof(float));
    uint32_t* mirA    = (uint32_t*)carve((size_t)N * (H / 2) * sizeof(uint32_t));
    uint32_t* mirB    = (uint32_t*)carve((size_t)N * (H / 2) * sizeof(uint32_t));
    float*    nrm     = (float*)carve((size_t)N * sizeof(float));
    float*    degc    = (float*)carve((size_t)N * sizeof(float));
    int*      pred    = (int*)  carve((size_t)N * sizeof(int));
    float*    f1      = (float*)carve((size_t)N * sizeof(float));
    float*    f2      = (float*)carve((size_t)N * sizeof(float));
    int*      deg     = (int*)  carve((size_t)N * sizeof(int));
    int*      row_ptr = (int*)  carve((size_t)(N + 1) * sizeof(int));
    int*      row_cur = (int*)  carve((size_t)N * sizeof(int));
    int*      bsum    = (int*)  carve((size_t)1024 * sizeof(int));
    int*      csr_src = (int*)  carve((size_t)E * sizeof(int));
    double*   stats   = (double*)carve((size_t)KITER * 8 * sizeof(double));

    const int TB = 256;
    int gN = (N + TB - 1) / TB;   // also nb for the scan
    int gE = (E + TB - 1) / TB;
    int gN64 = (N + 63) / 64;     // TB=64 grids for predG/edge

    k_zero<<<gN, TB, 0, stream>>>(deg, stats, N, KITER * 8);
    k_degcount<<<gE, TB, 0, stream>>>(dst, deg, E);
    k_blocksum<<<gN, TB, 0, stream>>>(deg, bsum, N);
    k_scanb<<<1, 512, 0, stream>>>(bsum, bsum + 512, row_ptr, gN, N);
    k_fill<<<gN, TB, 0, stream>>>(deg, bsum + 512, row_ptr, row_cur, N);
    k_norm<<<gN, TB, 0, stream>>>(deg, degc, nrm, N);
    int nchunk = (E + SCHUNK - 1) / SCHUNK;
    int slice_sz = (N + 7) / 8;
    k_scatter8<<<nchunk * 8, TB, 0, stream>>>(src, dst, row_cur, csr_src, E, slice_sz);
    int n4 = N * (H / 4);
    k_scale<<<(n4 + TB - 1) / TB, TB, 0, stream>>>(feat, nrm, featnA, mirA, n4);

    const float* cur = featnA;     // featn_0 (f32 master)
    const uint32_t* mcur = mirA;   // fp16 mirror of cur
    int gWave = (N + 3) / 4;       // wave-per-node: 4 nodes / 256-thread block
    for (int l = 0; l < KITER; ++l) {
        int last = (l == KITER - 1);
        float* nxt = last ? out : ((l % 2 == 0) ? featnB : featnA);
        uint32_t* mnxt = (l % 2 == 0) ? mirB : mirA;  // unused when last
        if (l == 0)
            k_pred0<<<gWave, TB, 0, stream>>>(logits, pred, N);
        else
            k_predG<<<gN64, 64, 0, stream>>>(cur, w_y, b_y, pred, N);
        k_edge<<<gN64, 64, 0, stream>>>(row_ptr, csr_src, pred, degc, f1, f2,
                                        stats + (size_t)l * 8, N);
        k_spmm<<<gWave, TB, 0, stream>>>(cur, mcur, nxt, mnxt, nrm, row_ptr, csr_src,
                                         f1, f2, stats + (size_t)l * 8, tau1, tau2,
                                         N, (float)N, last);
        cur = nxt;
        mcur = mnxt;
    }
}

// Round 9
// 1619.052 us; speedup vs baseline: 1.1671x; 1.1671x over previous
//
#include <hip/hip_runtime.h>
#include <hip/hip_fp16.h>
#include <cstdint>
#include <cstddef>

#define H 128
#define C 64
#define KITER 10
#define SCHUNK 4096

// ---------------- setup kernels ----------------

__global__ void k_zero(int* __restrict__ deg, double* __restrict__ stats, int n, int nstats) {
    int i = blockIdx.x * blockDim.x + threadIdx.x;
    if (i < n) deg[i] = 0;
    if (i < nstats) stats[i] = 0.0;
}

__global__ void k_degcount(const int* __restrict__ dst, int* __restrict__ deg, int E) {
    int e = blockIdx.x * blockDim.x + threadIdx.x;
    if (e < E) atomicAdd(&deg[dst[e]], 1);
}

// ---- multi-block exclusive scan of deg -> row_ptr/row_cur ----

__global__ __launch_bounds__(256) void k_blocksum(const int* __restrict__ deg,
                                                  int* __restrict__ bsum, int n) {
    __shared__ int red[256];
    int t = threadIdx.x;
    int i = blockIdx.x * 256 + t;
    red[t] = (i < n) ? deg[i] : 0;
    __syncthreads();
    for (int off = 128; off >= 1; off >>= 1) {
        if (t < off) red[t] += red[t + off];
        __syncthreads();
    }
    if (t == 0) bsum[blockIdx.x] = red[0];
}

__global__ __launch_bounds__(512) void k_scanb(const int* __restrict__ bsum,
                                               int* __restrict__ boff,
                                               int* __restrict__ row_ptr, int nb, int n) {
    __shared__ int s[512];
    int t = threadIdx.x;
    int v = (t < nb) ? bsum[t] : 0;
    s[t] = v;
    __syncthreads();
    for (int off = 1; off < 512; off <<= 1) {
        int u = (t >= off) ? s[t - off] : 0;
        __syncthreads();
        s[t] += u;
        __syncthreads();
    }
    if (t < nb) boff[t] = s[t] - v;  // exclusive
    if (t == 511) row_ptr[n] = s[511];
}

__global__ __launch_bounds__(256) void k_fill(const int* __restrict__ deg,
                                              const int* __restrict__ boff,
                                              int* __restrict__ row_ptr,
                                              int* __restrict__ row_cur, int n) {
    __shared__ int s[256];
    int t = threadIdx.x;
    int i = blockIdx.x * 256 + t;
    int d = (i < n) ? deg[i] : 0;
    s[t] = d;
    __syncthreads();
    for (int off = 1; off < 256; off <<= 1) {
        int u = (t >= off) ? s[t - off] : 0;
        __syncthreads();
        s[t] += u;
        __syncthreads();
    }
    if (i < n) {
        int base = boff[blockIdx.x] + s[t] - d;
        row_ptr[i] = base;
        row_cur[i] = base;
    }
}

__global__ void k_norm(const int* __restrict__ deg, float* __restrict__ degc,
                       float* __restrict__ nrm, int n) {
    int i = blockIdx.x * blockDim.x + threadIdx.x;
    if (i < n) {
        int d = deg[i];
        float dc = (float)(d > 1 ? d : 1);
        degc[i] = dc;
        nrm[i] = (float)(1.0 / sqrt((double)dc));  // correctly-rounded dc^-0.5
    }
}

// XCD-sliced scatter (R4: confirmed WRITE_SIZE collapse).
__global__ __launch_bounds__(256) void k_scatter8(const int* __restrict__ src,
                                                  const int* __restrict__ dst,
                                                  int* __restrict__ row_cur,
                                                  int* __restrict__ csr_src,
                                                  int E, int slice_sz) {
    int chunk = blockIdx.x >> 3;
    int xcd = blockIdx.x & 7;
    int base = chunk * SCHUNK;
    int lo_node = xcd * slice_sz;
    int hi_node = lo_node + slice_sz;
    #pragma unroll
    for (int r = 0; r < SCHUNK; r += 256) {
        int e = base + r + threadIdx.x;
        if (e < E) {
            int d = dst[e];
            if (d >= lo_node && d < hi_node) {
                int pos = atomicAdd(&row_cur[d], 1);
                csr_src[pos] = src[e];
            }
        }
    }
}

__device__ inline uint32_t pack_h2(float x, float y) {
    __half2 h = __floats2half2_rn(x, y);
    return __builtin_bit_cast(uint32_t, h);
}
__device__ inline float2 unpack_h2(uint32_t p) {
    __half2 h = __builtin_bit_cast(__half2, p);
    return __half22float2(h);
}

// featn0 = feat * norm (f32 master) + fp16 mirror. thread per float4.
__global__ __launch_bounds__(256) void k_scale(const float* __restrict__ feat,
                                               const float* __restrict__ nrm,
                                               float* __restrict__ featn,
                                               uint32_t* __restrict__ mir, int n4) {
    int i = blockIdx.x * blockDim.x + threadIdx.x;
    if (i >= n4) return;
    int node = i >> 5;  // 32 float4 per row (H=128)
    float nn = nrm[node];
    float4 v = ((const float4*)feat)[i];
    v.x *= nn; v.y *= nn; v.z *= nn; v.w *= nn;
    ((float4*)featn)[i] = v;
    mir[i * 2]     = pack_h2(v.x, v.y);
    mir[i * 2 + 1] = pack_h2(v.z, v.w);
}

// ---------------- per-iteration kernels ----------------

__global__ __launch_bounds__(256) void k_pred0(const float* __restrict__ logits,
                                               int* __restrict__ pred, int n) {
    int wid = (blockIdx.x * blockDim.x + threadIdx.x) >> 6;
    int lane = threadIdx.x & 63;
    if (wid >= n) return;
    float v = logits[(size_t)wid * C + lane];
    int idx = lane;
    #pragma unroll
    for (int off = 1; off < 64; off <<= 1) {
        float ov = __shfl_xor(v, off);
        int oi = __shfl_xor(idx, off);
        if (ov > v || (ov == v && oi < idx)) { v = ov; idx = oi; }
    }
    if (lane == 0) pred[wid] = idx;
}

// thread-per-node logits = featn@w + b, pred = argmax (featn f32 master).
// TB=256 (R8 showed TB=64 1-wave workgroups regress ~2x: all 391 blocks of
// the 256-thread grid are co-resident anyway at ~3 blocks/CU).
__global__ __launch_bounds__(256) void k_predG(const float* __restrict__ featn,
                                               const float* __restrict__ w_y,
                                               const float* __restrict__ b_y,
                                               int* __restrict__ pred, int n) {
    int node = blockIdx.x * blockDim.x + threadIdx.x;
    bool act = node < n;
    int ld = act ? node : 0;
    const float4* p4 = (const float4*)(featn + (size_t)ld * H);
    float fv[H];
    #pragma unroll
    for (int q = 0; q < H / 4; ++q) {
        float4 t = p4[q];
        fv[q * 4 + 0] = t.x;
        fv[q * 4 + 1] = t.y;
        fv[q * 4 + 2] = t.z;
        fv[q * 4 + 3] = t.w;
    }
    float best = -3.402823466e+38f;
    int bi = 0;
    for (int cb = 0; cb < C / 8; ++cb) {
        float acc[8];
        #pragma unroll
        for (int u = 0; u < 8; ++u) acc[u] = 0.f;
        const float* wp = w_y + cb * 8;
        #pragma unroll
        for (int h = 0; h < H; ++h) {
            #pragma unroll
            for (int u = 0; u < 8; ++u)
                acc[u] = fmaf(fv[h], wp[h * C + u], acc[u]);
        }
        #pragma unroll
        for (int u = 0; u < 8; ++u) {
            float val = acc[u] + b_y[cb * 8 + u];
            int c = cb * 8 + u;
            if (val > best) { best = val; bi = c; }  // strict > keeps first index
        }
    }
    if (act) pred[node] = bi;
}

// Thread-per-node edge features (TB=256), present-classes-only entropy via
// seen-mask, per-wave f64 butterfly + 1 barrier for the 4 stat sums.
__global__ __launch_bounds__(256) void k_edge(const int* __restrict__ row_ptr,
                                              const int* __restrict__ csr_src,
                                              const int* __restrict__ pred,
                                              const float* __restrict__ degc,
                                              float* __restrict__ f1, float* __restrict__ f2,
                                              double* __restrict__ stats_iter, int n) {
    __shared__ unsigned char hist[256][64];
    __shared__ double wred[4][4];  // [wave][stat]
    int t = threadIdx.x;
    int node = blockIdx.x * 256 + t;
    uint32_t* hp = (uint32_t*)hist[t];
    #pragma unroll
    for (int q = 0; q < 16; ++q) hp[q] = 0u;
    float v1 = 0.f, v2 = 0.f;
    bool act = node < n;
    if (act) {
        int lo = row_ptr[node], hi = row_ptr[node + 1];
        int pc = pred[node];
        int eq = 0;
        uint64_t seen = 0;
        for (int j = lo; j < hi; ++j) {
            int p = pred[csr_src[j]];
            eq += (p == pc) ? 1 : 0;
            hist[t][p] += 1;
            seen |= 1ull << p;
        }
        float dc = degc[node];
        v1 = (float)eq / dc;
        int nnz = __popcll(seen);
        float s = 0.f;
        uint64_t m = seen;
        while (m) {
            int c = __builtin_ctzll(m);
            m &= m - 1;
            float cv = (float)hist[t][c] / dc;  // >= 1/dc >> 1e-5, clamp dead
            s += cv * logf(cv);
        }
        const float c0 = 1e-5f * -11.5129251f;  // 1e-5*ln(1e-5) in f32
        s += (float)(64 - nnz) * c0;
        v2 = -s;
        f1[node] = v1;
        f2[node] = v2;
    }
    double vals[4];
    vals[0] = act ? (double)v1 : 0.0;
    vals[1] = vals[0] * vals[0];
    vals[2] = act ? (double)v2 : 0.0;
    vals[3] = vals[2] * vals[2];
    #pragma unroll
    for (int q = 0; q < 4; ++q) {
        #pragma unroll
        for (int off = 1; off < 64; off <<= 1)
            vals[q] += __shfl_xor(vals[q], off);
    }
    if ((t & 63) == 0) {
        int wv = t >> 6;
        #pragma unroll
        for (int q = 0; q < 4; ++q) wred[wv][q] = vals[q];
    }
    __syncthreads();
    if (t < 4) {
        double sum = wred[0][t] + wred[1][t] + wred[2][t] + wred[3][t];
        atomicAdd(&stats_iter[t], sum);
    }
}

// SpMM gathering from fp16 mirror, f32 accumulate, + z + residual on f32
// master. f32 LN finalize (R8: confirmed −4 µs/iter vs f64). Gather loop
// unrolled 8/4/1 for deeper MLP (VALUBusy was 52% with 4 in flight).
__global__ __launch_bounds__(256) void k_spmm(const float* __restrict__ featn,
                                              const uint32_t* __restrict__ mir_cur,
                                              float* __restrict__ nxt,
                                              uint32_t* __restrict__ mir_nxt,
                                              const float* __restrict__ nrm,
                                              const int* __restrict__ row_ptr,
                                              const int* __restrict__ csr_src,
                                              const float* __restrict__ f1,
                                              const float* __restrict__ f2,
                                              const double* __restrict__ stats_iter,
                                              const float* __restrict__ tau1,
                                              const float* __restrict__ tau2,
                                              int n, float fN, int last) {
    int wid = (blockIdx.x * blockDim.x + threadIdx.x) >> 6;
    int lane = threadIdx.x & 63;
    if (wid >= n) return;
    int node = __builtin_amdgcn_readfirstlane(wid);

    // z from global-LN(f1), LN(f2) stats (f32 math on f64 sums)
    float S1 = (float)stats_iter[0], Q1 = (float)stats_iter[1];
    float S2 = (float)stats_iter[2], Q2 = (float)stats_iter[3];
    float m1 = S1 / fN, m2 = S2 / fN;
    float rs1 = 1.0f / sqrtf(Q1 / fN - m1 * m1 + 1e-5f);
    float rs2 = 1.0f / sqrtf(Q2 / fN - m2 * m2 + 1e-5f);
    float ln1 = (f1[node] - m1) * rs1;
    float ln2 = (f2[node] - m2) * rs2;
    float z1 = 1.f / (1.f + expf(ln1 - tau1[0]));  // sigmoid(-(ln1 - tau1))
    float z2 = 1.f / (1.f + expf(ln2 - tau2[0]));
    float z = z1 * z2;

    float nr = nrm[node];
    int lo = row_ptr[node], hi = row_ptr[node + 1];
    float ax = 0.f, ay = 0.f;
    const uint32_t* basep = mir_cur + lane;  // row stride = 64 dwords (128 halves)
    int j = lo;
    for (; j + 7 < hi; j += 8) {
        uint32_t p0 = basep[(size_t)csr_src[j]     * 64];
        uint32_t p1 = basep[(size_t)csr_src[j + 1] * 64];
        uint32_t p2 = basep[(size_t)csr_src[j + 2] * 64];
        uint32_t p3 = basep[(size_t)csr_src[j + 3] * 64];
        uint32_t p4 = basep[(size_t)csr_src[j + 4] * 64];
        uint32_t p5 = basep[(size_t)csr_src[j + 5] * 64];
        uint32_t p6 = basep[(size_t)csr_src[j + 6] * 64];
        uint32_t p7 = basep[(size_t)csr_src[j + 7] * 64];
        float2 g0 = unpack_h2(p0); ax += g0.x; ay += g0.y;
        float2 g1 = unpack_h2(p1); ax += g1.x; ay += g1.y;
        float2 g2 = unpack_h2(p2); ax += g2.x; ay += g2.y;
        float2 g3 = unpack_h2(p3); ax += g3.x; ay += g3.y;
        float2 g4 = unpack_h2(p4); ax += g4.x; ay += g4.y;
        float2 g5 = unpack_h2(p5); ax += g5.x; ay += g5.y;
        float2 g6 = unpack_h2(p6); ax += g6.x; ay += g6.y;
        float2 g7 = unpack_h2(p7); ax += g7.x; ay += g7.y;
    }
    for (; j + 3 < hi; j += 4) {
        uint32_t p0 = basep[(size_t)csr_src[j]     * 64];
        uint32_t p1 = basep[(size_t)csr_src[j + 1] * 64];
        uint32_t p2 = basep[(size_t)csr_src[j + 2] * 64];
        uint32_t p3 = basep[(size_t)csr_src[j + 3] * 64];
        float2 g0 = unpack_h2(p0); ax += g0.x; ay += g0.y;
        float2 g1 = unpack_h2(p1); ax += g1.x; ay += g1.y;
        float2 g2 = unpack_h2(p2); ax += g2.x; ay += g2.y;
        float2 g3 = unpack_h2(p3); ax += g3.x; ay += g3.y;
    }
    for (; j < hi; ++j) {
        float2 g0 = unpack_h2(basep[(size_t)csr_src[j] * 64]);
        ax += g0.x; ay += g0.y;
    }
    const float2 ownn = *(const float2*)(featn + (size_t)node * H + lane * 2);
    float ox = fmaf(z, ax * nr, ownn.x);
    float oy = fmaf(z, ay * nr, ownn.y);
    if (!last) {
        ox *= nr; oy *= nr;  // pre-apply next iter's leading feat*norm
        mir_nxt[(size_t)node * 64 + lane] = pack_h2(ox, oy);
    }
    float2 o; o.x = ox; o.y = oy;
    *(float2*)(nxt + (size_t)node * H + lane * 2) = o;
}

// ---------------- host ----------------

extern "C" void kernel_launch(void* const* d_in, const int* in_sizes, int n_in,
                              void* d_out, int out_size, void* d_ws, size_t ws_size,
                              hipStream_t stream) {
    const float* feat   = (const float*)d_in[0];
    const float* logits = (const float*)d_in[1];
    const float* w_y    = (const float*)d_in[2];
    const float* b_y    = (const float*)d_in[3];
    const float* tau1   = (const float*)d_in[4];
    const float* tau2   = (const float*)d_in[5];
    const int*   src    = (const int*)d_in[6];
    const int*   dst    = (const int*)d_in[7];

    const int N = in_sizes[0] / H;
    const int E = in_sizes[6];
    float* out = (float*)d_out;

    char* ws = (char*)d_ws;
    size_t off = 0;
    auto carve = [&](size_t bytes) -> char* {
        char* p = ws + off;
        off = (off + bytes + 255) & ~(size_t)255;
        return p;
    };
    float*    featnA  = (float*)carve((size_t)N * H * sizeof(float));
    float*    featnB  = (float*)carve((size_t)N * H * sizeof(float));
    uint32_t* mirA    = (uint32_t*)carve((size_t)N * (H / 2) * sizeof(uint32_t));
    uint32_t* mirB    = (uint32_t*)carve((size_t)N * (H / 2) * sizeof(uint32_t));
    float*    nrm     = (float*)carve((size_t)N * sizeof(float));
    float*    degc    = (float*)carve((size_t)N * sizeof(float));
    int*      pred    = (int*)  carve((size_t)N * sizeof(int));
    float*    f1      = (float*)carve((size_t)N * sizeof(float));
    float*    f2      = (float*)carve((size_t)N * sizeof(float));
    int*      deg     = (int*)  carve((size_t)N * sizeof(int));
    int*      row_ptr = (int*)  carve((size_t)(N + 1) * sizeof(int));
    int*      row_cur = (int*)  carve((size_t)N * sizeof(int));
    int*      bsum    = (int*)  carve((size_t)1024 * sizeof(int));
    int*      csr_src = (int*)  carve((size_t)E * sizeof(int));
    double*   stats   = (double*)carve((size_t)KITER * 8 * sizeof(double));

    const int TB = 256;
    int gN = (N + TB - 1) / TB;   // also nb for the scan
    int gE = (E + TB - 1) / TB;

    k_zero<<<gN, TB, 0, stream>>>(deg, stats, N, KITER * 8);
    k_degcount<<<gE, TB, 0, stream>>>(dst, deg, E);
    k_blocksum<<<gN, TB, 0, stream>>>(deg, bsum, N);
    k_scanb<<<1, 512, 0, stream>>>(bsum, bsum + 512, row_ptr, gN, N);
    k_fill<<<gN, TB, 0, stream>>>(deg, bsum + 512, row_ptr, row_cur, N);
    k_norm<<<gN, TB, 0, stream>>>(deg, degc, nrm, N);
    int nchunk = (E + SCHUNK - 1) / SCHUNK;
    int slice_sz = (N + 7) / 8;
    k_scatter8<<<nchunk * 8, TB, 0, stream>>>(src, dst, row_cur, csr_src, E, slice_sz);
    int n4 = N * (H / 4);
    k_scale<<<(n4 + TB - 1) / TB, TB, 0, stream>>>(feat, nrm, featnA, mirA, n4);

    const float* cur = featnA;     // featn_0 (f32 master)
    const uint32_t* mcur = mirA;   // fp16 mirror of cur
    int gWave = (N + 3) / 4;       // wave-per-node: 4 nodes / 256-thread block
    for (int l = 0; l < KITER; ++l) {
        int last = (l == KITER - 1);
        float* nxt = last ? out : ((l % 2 == 0) ? featnB : featnA);
        uint32_t* mnxt = (l % 2 == 0) ? mirB : mirA;  // unused when last
        if (l == 0)
            k_pred0<<<gWave, TB, 0, stream>>>(logits, pred, N);
        else
            k_predG<<<gN, TB, 0, stream>>>(cur, w_y, b_y, pred, N);
        k_edge<<<gN, TB, 0, stream>>>(row_ptr, csr_src, pred, degc, f1, f2,
                                      stats + (size_t)l * 8, N);
        k_spmm<<<gWave, TB, 0, stream>>>(cur, mcur, nxt, mnxt, nrm, row_ptr, csr_src,
                                         f1, f2, stats + (size_t)l * 8, tau1, tau2,
                                         N, (float)N, last);
        cur = nxt;
        mcur = mnxt;
    }
}